// Round 16
// baseline (551.584 us; speedup 1.0000x reference)
//
#include <hip/hip_runtime.h>

#define NN 32768
#define NE 131072
#define NB 512
#define SL 1000

using bf16x8 = __attribute__((ext_vector_type(8))) short;
using f32x4  = __attribute__((ext_vector_type(4))) float;

static __device__ __forceinline__ unsigned short f2b(float f) {
  union { float f; unsigned u; } x; x.f = f;
  unsigned r = x.u + 0x7fffu + ((x.u >> 16) & 1u);  // RNE
  return (unsigned short)(r >> 16);
}

static __device__ __forceinline__ void bn_from_raw(float sum, float ssq, float g, float b,
                                                   float& sc, float& sh) {
  float m = sum / 32768.f;
  float v = ssq / 32768.f - m * m;
  sc = g * rsqrtf(v + 1e-5f);
  sh = b - m * sc;
}

// ---------------- fused degree + conv-weight prep ----------------
__global__ void k_degprep(const int* __restrict__ dst, int* __restrict__ degi,
                          const float* __restrict__ emb, const float* __restrict__ ck1,
                          const float* __restrict__ ck2, const float* __restrict__ ck3,
                          unsigned short* __restrict__ emb_bf, unsigned short* __restrict__ wt1,
                          unsigned short* __restrict__ wt2, unsigned short* __restrict__ wt3) {
  int gid = blockIdx.x * 256 + threadIdx.x;
  atomicAdd(&degi[dst[gid]], 1);
  int idx = gid;
  if (idx < 3328) {
    emb_bf[idx] = f2b(emb[idx]);
  } else if (idx < 3328 + 16384) {
    int i = idx - 3328;
    int kt = i >> 12, co = (i >> 7) & 31, ci = i & 127;
    wt1[i] = f2b(ck1[co * 512 + ci * 4 + kt]);
  } else if (idx < 3328 + 16384 + 12288) {
    int i = idx - 3328 - 16384;
    int kt = i >> 11, co = (i >> 5) & 63, ci = i & 31;
    wt2[i] = f2b(ck2[co * 192 + ci * 6 + kt]);
  } else if (idx < 3328 + 16384 + 12288 + 49152) {
    int i = idx - 3328 - 16384 - 12288;
    int kt = i / 6144, co = (i >> 6) % 96, ci = i & 63;
    wt3[i] = f2b(ck3[co * 512 + ci * 8 + kt]);
  }
}

__global__ void k_scan(const int* __restrict__ degi, int* __restrict__ base,
                       int* __restrict__ cursor, float* __restrict__ dis) {
  __shared__ int part[1024];
  int tid = threadIdx.x;
  int v[32];
  int s = 0;
  int lo = tid * 32;
#pragma unroll
  for (int i = 0; i < 32; ++i) { v[i] = degi[lo + i]; s += v[i]; }
  part[tid] = s;
  __syncthreads();
  for (int off = 1; off < 1024; off <<= 1) {
    int val = (tid >= off) ? part[tid - off] : 0;
    __syncthreads();
    part[tid] += val;
    __syncthreads();
  }
  int run = (tid > 0) ? part[tid - 1] : 0;
#pragma unroll
  for (int i = 0; i < 32; ++i) {
    base[lo + i] = run;
    cursor[lo + i] = run;
    dis[lo + i] = rsqrtf(1.0f + (float)v[i]);
    run += v[i];
  }
  if (tid == 1023) base[NN] = run;
}

__global__ void k_fill(const int* __restrict__ src, const int* __restrict__ dst,
                       int* __restrict__ cursor, unsigned short* __restrict__ csr_src, int E) {
  int e = blockIdx.x * 256 + threadIdx.x;
  if (e < E) {
    int d = dst[e];
    int pos = atomicAdd(&cursor[d], 1);
    csr_src[pos] = (unsigned short)src[e];
  }
}

// ---------------- L1: aggregate(x,5ch) + 5->64 fc + fused stats ----------------
__launch_bounds__(256)
__global__ void k_gfc1s(const float* __restrict__ x, const float* __restrict__ dis,
                        const int* __restrict__ base, const unsigned short* __restrict__ csr_src,
                        const float* __restrict__ W1, float* __restrict__ out,
                        float* __restrict__ st) {
  __shared__ float sW[5][64];
  __shared__ float a5[256][6];
  __shared__ float red[16][64];
  int tid = threadIdx.x;
  for (int i = tid; i < 320; i += 256) sW[i >> 6][i & 63] = W1[i];
  int n = blockIdx.x * 256 + tid;
  float dn = dis[n];
  float s2 = dn * dn;
  const float* xn = x + (long)n * 5;
  float a0 = xn[0] * s2, a1 = xn[1] * s2, a2 = xn[2] * s2, a3 = xn[3] * s2, a4 = xn[4] * s2;
  int b0 = base[n], b1 = base[n + 1];
  int sNext = (b0 < b1) ? csr_src[b0] : 0;
  for (int j = b0; j < b1; ++j) {
    int s = sNext;
    if (j + 1 < b1) sNext = csr_src[j + 1];
    float coef = dis[s] * dn;
    const float* xs = x + (long)s * 5;
    a0 += xs[0] * coef; a1 += xs[1] * coef; a2 += xs[2] * coef;
    a3 += xs[3] * coef; a4 += xs[4] * coef;
  }
  a5[tid][0] = a0; a5[tid][1] = a1; a5[tid][2] = a2; a5[tid][3] = a3; a5[tid][4] = a4;
  __syncthreads();
  int co = (tid & 15) * 4, strip = tid >> 4;
  float4 s4 = {0.f, 0.f, 0.f, 0.f}, ss4 = {0.f, 0.f, 0.f, 0.f};
  for (int i = 0; i < 16; ++i) {
    int nl = strip * 16 + i;
    long nn = (long)blockIdx.x * 256 + nl;
    float4 acc = {0.f, 0.f, 0.f, 0.f};
#pragma unroll
    for (int ci = 0; ci < 5; ++ci) {
      float av = a5[nl][ci];
      acc.x += av * sW[ci][co];     acc.y += av * sW[ci][co + 1];
      acc.z += av * sW[ci][co + 2]; acc.w += av * sW[ci][co + 3];
    }
    *(float4*)&out[nn * 64 + co] = acc;
    s4.x += acc.x; s4.y += acc.y; s4.z += acc.z; s4.w += acc.w;
    ss4.x += acc.x * acc.x; ss4.y += acc.y * acc.y;
    ss4.z += acc.z * acc.z; ss4.w += acc.w * acc.w;
  }
  *(float4*)&red[strip][co] = s4;
  __syncthreads();
  if (tid < 64) {
    float t = 0.f;
#pragma unroll
    for (int s = 0; s < 16; ++s) t += red[s][tid];
    atomicAdd(&st[tid], t);
  }
  __syncthreads();
  *(float4*)&red[strip][co] = ss4;
  __syncthreads();
  if (tid < 64) {
    float t = 0.f;
#pragma unroll
    for (int s = 0; s < 16; ++s) t += red[s][tid];
    atomicAdd(&st[64 + tid], t);
  }
}

// ---------------- gather with BN-on-load (raw-sum stats), index prefetch ----------------
template<int C>
__launch_bounds__(256)
__global__ void k_gbngather(const float* __restrict__ in, const float* __restrict__ dis,
                            const int* __restrict__ base, const unsigned short* __restrict__ csr_src,
                            const float* __restrict__ st, const float* __restrict__ g,
                            const float* __restrict__ bt, float* __restrict__ out) {
  constexpr int TPN = C / 4;
  int t = blockIdx.x * 256 + threadIdx.x;
  int n = t / TPN;
  int c = (t % TPN) * 4;
  float4 sum4 = *(const float4*)&st[c];
  float4 ssq4 = *(const float4*)&st[C + c];
  float4 gg = *(const float4*)&g[c];
  float4 bb = *(const float4*)&bt[c];
  float4 sc4, sh4;
  bn_from_raw(sum4.x, ssq4.x, gg.x, bb.x, sc4.x, sh4.x);
  bn_from_raw(sum4.y, ssq4.y, gg.y, bb.y, sc4.y, sh4.y);
  bn_from_raw(sum4.z, ssq4.z, gg.z, bb.z, sc4.z, sh4.z);
  bn_from_raw(sum4.w, ssq4.w, gg.w, bb.w, sc4.w, sh4.w);
  float dn = dis[n];
  float s2 = dn * dn;
  float4 a = *(const float4*)&in[(long)n * C + c];
  float4 acc;
  acc.x = fmaxf(a.x * sc4.x + sh4.x, 0.f) * s2;
  acc.y = fmaxf(a.y * sc4.y + sh4.y, 0.f) * s2;
  acc.z = fmaxf(a.z * sc4.z + sh4.z, 0.f) * s2;
  acc.w = fmaxf(a.w * sc4.w + sh4.w, 0.f) * s2;
  int b0 = base[n], b1 = base[n + 1];
  int sNext = (b0 < b1) ? csr_src[b0] : 0;
  for (int j = b0; j < b1; ++j) {
    int s = sNext;
    if (j + 1 < b1) sNext = csr_src[j + 1];
    float coef = dis[s] * dn;
    float4 vv = *(const float4*)&in[(long)s * C + c];
    acc.x += fmaxf(vv.x * sc4.x + sh4.x, 0.f) * coef;
    acc.y += fmaxf(vv.y * sc4.y + sh4.y, 0.f) * coef;
    acc.z += fmaxf(vv.z * sc4.z + sh4.z, 0.f) * coef;
    acc.w += fmaxf(vv.w * sc4.w + sh4.w, 0.f) * coef;
  }
  *(float4*)&out[(long)n * C + c] = acc;
}

// ---------------- register-tiled dense layer, optional fused stats ----------------
template<int C_OUT, int K, int TN, bool RELU, bool BIAS, bool STATS>
__launch_bounds__(256)
__global__ void k_fc4(const float* __restrict__ in, const float* __restrict__ W,
                      const float* __restrict__ bias, float* __restrict__ out,
                      float* __restrict__ st, int N) {
  constexpr int CO4 = C_OUT / 4;
  constexpr int GPB = 256 / CO4;
  int g = blockIdx.x * GPB + threadIdx.x / CO4;
  long n0 = (long)g * TN;
  if (!STATS && n0 >= N) return;
  int co = (threadIdx.x % CO4) * 4;
  float4 acc[TN];
  float4 b4 = {0.f, 0.f, 0.f, 0.f};
  if (BIAS) b4 = *(const float4*)&bias[co];
#pragma unroll
  for (int t = 0; t < TN; ++t) acc[t] = b4;
  for (int ci = 0; ci < K; ci += 4) {
    float4 w0 = *(const float4*)&W[(long)(ci + 0) * C_OUT + co];
    float4 w1 = *(const float4*)&W[(long)(ci + 1) * C_OUT + co];
    float4 w2 = *(const float4*)&W[(long)(ci + 2) * C_OUT + co];
    float4 w3 = *(const float4*)&W[(long)(ci + 3) * C_OUT + co];
#pragma unroll
    for (int t = 0; t < TN; ++t) {
      float4 a = *(const float4*)&in[(n0 + t) * K + ci];
      acc[t].x += a.x * w0.x; acc[t].y += a.x * w0.y; acc[t].z += a.x * w0.z; acc[t].w += a.x * w0.w;
      acc[t].x += a.y * w1.x; acc[t].y += a.y * w1.y; acc[t].z += a.y * w1.z; acc[t].w += a.y * w1.w;
      acc[t].x += a.z * w2.x; acc[t].y += a.z * w2.y; acc[t].z += a.z * w2.z; acc[t].w += a.z * w2.w;
      acc[t].x += a.w * w3.x; acc[t].y += a.w * w3.y; acc[t].z += a.w * w3.z; acc[t].w += a.w * w3.w;
    }
  }
  float4 s4 = {0.f, 0.f, 0.f, 0.f}, ss4 = {0.f, 0.f, 0.f, 0.f};
#pragma unroll
  for (int t = 0; t < TN; ++t) {
    float4 o = acc[t];
    if (RELU) {
      o.x = fmaxf(o.x, 0.f); o.y = fmaxf(o.y, 0.f);
      o.z = fmaxf(o.z, 0.f); o.w = fmaxf(o.w, 0.f);
    }
    *(float4*)&out[(n0 + t) * C_OUT + co] = o;
    if (STATS) {
      s4.x += o.x; s4.y += o.y; s4.z += o.z; s4.w += o.w;
      ss4.x += o.x * o.x; ss4.y += o.y * o.y;
      ss4.z += o.z * o.z; ss4.w += o.w * o.w;
    }
  }
  if (STATS) {
    __shared__ float red2[GPB][C_OUT];
    int grp = threadIdx.x / CO4;
    *(float4*)&red2[grp][co] = s4;
    __syncthreads();
    if (threadIdx.x < C_OUT) {
      float t = 0.f;
#pragma unroll
      for (int s = 0; s < GPB; ++s) t += red2[s][threadIdx.x];
      atomicAdd(&st[threadIdx.x], t);
    }
    __syncthreads();
    *(float4*)&red2[grp][co] = ss4;
    __syncthreads();
    if (threadIdx.x < C_OUT) {
      float t = 0.f;
#pragma unroll
      for (int s = 0; s < GPB; ++s) t += red2[s][threadIdx.x];
      atomicAdd(&st[C_OUT + threadIdx.x], t);
    }
  }
}

// ---------------- protein encoder: bf16 MFMA, 51.3KB LDS (3 blocks/CU) + fused pool ----------------
// Single manually-carved shared array (ushort offsets):
//   weight area [0, 8704): wt1 slices 2x4352 | wt2 slices 2x2560 | wt3 buf0 @0
//   wt3 buf1 @6912 (spans into s_c1's region — s_c1 is dead during conv3)
//   s_c1 @8704 (152 rows x 40), guard rows 144..151 zeroed
//   s_c2 @14784 (144 rows x 72)
//   tok ints @int 12576 (152), max ints @12728 (96), pool lo/hi @12824/12825
// wt1/wt2 kt-slice double-buffered (prefetch-into-regs, like wt3) — keeps all
// per-accumulator MFMA chain orders identical to r15 (kt outer, cb inner).
__launch_bounds__(256)
__global__ void conv_mfma(const int* __restrict__ seq, const unsigned short* __restrict__ emb_bf,
                          const unsigned short* __restrict__ wt1g, const float* __restrict__ cb1,
                          const unsigned short* __restrict__ wt2g, const float* __restrict__ cb2,
                          const unsigned short* __restrict__ wt3g, const float* __restrict__ cb3,
                          const float* __restrict__ agg, const float* __restrict__ st3,
                          const float* __restrict__ g3, const float* __restrict__ bt3,
                          const int* __restrict__ batch, float* __restrict__ outmax) {
  __shared__ __align__(16) unsigned short S[25664];
  int* Si = (int*)S;
  const int C1 = 8704, C2 = 14784, TOKI = 12576, MAXI = 12728;

  int tid = threadIdx.x;
  int b = blockIdx.y;

  if (blockIdx.x == 8) {  // ---- pooling block (BN3 + relu + mean over batch range)
    if (tid == 0) {
      int lo = 0, hi = NN;
      while (lo < hi) { int m = (lo + hi) >> 1; if (batch[m] < b) lo = m + 1; else hi = m; }
      Si[12824] = lo;
      hi = NN;
      while (lo < hi) { int m = (lo + hi) >> 1; if (batch[m] <= b) lo = m + 1; else hi = m; }
      Si[12825] = lo;
    }
    __syncthreads();
    if (tid < 128) {
      int lo = Si[12824], hi = Si[12825], c = tid;
      float sc, sh;
      bn_from_raw(st3[c], st3[128 + c], g3[c], bt3[c], sc, sh);
      float s = 0.f;
      for (int n = lo; n < hi; ++n) s += fmaxf(agg[(long)n * 128 + c] * sc + sh, 0.f);
      outmax[b * 224 + c] = s / fmaxf((float)(hi - lo), 1.0f);
    }
    return;
  }

  int t0 = blockIdx.x * 128;

  if (tid < 96) Si[MAXI + tid] = 0;
  if (tid < 152) {
    int p = t0 - 6 + tid;
    Si[TOKI + tid] = (p >= 0 && p < SL) ? seq[b * SL + p] : 0;
  }
  if (tid < 160) Si[7232 + tid] = 0;  // s_c1 guard rows 144..151 (320 ushorts)

  // stage wt1 slice 0 (512 chunks, 2/thread)
  for (int c = 0; c < 2; ++c) {
    int ch = c * 256 + tid;
    int row = ch >> 4, col8 = ch & 15;
    *(bf16x8*)&S[row * 136 + col8 * 8] = *(const bf16x8*)(wt1g + ch * 8);
  }
  __syncthreads();

  int lane = tid & 63, wave = tid >> 6;
  int l15 = lane & 15, quad = lane >> 4;

  // ---- conv1: kt-sliced wt1, acc for (2 mt) x (2 nt) + wave0 mt=8
  {
    int mt0 = wave, mt1 = wave + 4;
    f32x4 acc[2][2], acc8[2];
#pragma unroll
    for (int nt = 0; nt < 2; ++nt) {
      float bv = cb1[nt * 16 + l15];
      acc[0][nt] = (f32x4){bv, bv, bv, bv};
      acc[1][nt] = (f32x4){bv, bv, bv, bv};
      acc8[nt] = (f32x4){bv, bv, bv, bv};
    }
    for (int kt = 0; kt < 4; ++kt) {
      bf16x8 w1t[2];
      if (kt < 3) {
#pragma unroll
        for (int c = 0; c < 2; ++c)
          w1t[c] = *(const bf16x8*)(wt1g + (kt + 1) * 4096 + (c * 256 + tid) * 8);
      }
      int wb = (kt & 1) * 4352;
      const unsigned short* e0 = emb_bf + Si[TOKI + mt0 * 16 + l15 + kt] * 128 + quad * 8;
      const unsigned short* e1 = emb_bf + Si[TOKI + mt1 * 16 + l15 + kt] * 128 + quad * 8;
#pragma unroll
      for (int cb = 0; cb < 4; ++cb) {
        bf16x8 a0 = *(const bf16x8*)(e0 + cb * 32);
        bf16x8 a1 = *(const bf16x8*)(e1 + cb * 32);
#pragma unroll
        for (int nt = 0; nt < 2; ++nt) {
          bf16x8 bf = *(const bf16x8*)&S[wb + (nt * 16 + l15) * 136 + cb * 32 + quad * 8];
          acc[0][nt] = __builtin_amdgcn_mfma_f32_16x16x32_bf16(a0, bf, acc[0][nt], 0, 0, 0);
          acc[1][nt] = __builtin_amdgcn_mfma_f32_16x16x32_bf16(a1, bf, acc[1][nt], 0, 0, 0);
        }
      }
      if (wave == 0) {
        const unsigned short* e8 = emb_bf + Si[TOKI + 128 + l15 + kt] * 128 + quad * 8;
#pragma unroll
        for (int cb = 0; cb < 4; ++cb) {
          bf16x8 a8 = *(const bf16x8*)(e8 + cb * 32);
#pragma unroll
          for (int nt = 0; nt < 2; ++nt) {
            bf16x8 bf = *(const bf16x8*)&S[wb + (nt * 16 + l15) * 136 + cb * 32 + quad * 8];
            acc8[nt] = __builtin_amdgcn_mfma_f32_16x16x32_bf16(a8, bf, acc8[nt], 0, 0, 0);
          }
        }
      }
      if (kt < 3) {
        int wb2 = ((kt + 1) & 1) * 4352;
#pragma unroll
        for (int c = 0; c < 2; ++c) {
          int ch = c * 256 + tid;
          int row = ch >> 4, col8 = ch & 15;
          *(bf16x8*)&S[wb2 + row * 136 + col8 * 8] = w1t[c];
        }
      }
      __syncthreads();
    }
#pragma unroll
    for (int mb = 0; mb < 2; ++mb) {
      int mt = mb ? mt1 : mt0;
#pragma unroll
      for (int nt = 0; nt < 2; ++nt) {
        int co = nt * 16 + l15;
#pragma unroll
        for (int r = 0; r < 4; ++r) {
          int m = mt * 16 + quad * 4 + r;
          int l1 = t0 - 5 + m;
          unsigned short hv = f2b(fmaxf(acc[mb][nt][r], 0.f));
          S[C1 + m * 40 + co] = (l1 >= 0 && l1 < 999) ? hv : (unsigned short)0;
        }
      }
    }
    if (wave == 0) {
#pragma unroll
      for (int nt = 0; nt < 2; ++nt) {
        int co = nt * 16 + l15;
#pragma unroll
        for (int r = 0; r < 4; ++r) {
          int m = 128 + quad * 4 + r;
          int l1 = t0 - 5 + m;
          unsigned short hv = f2b(fmaxf(acc8[nt][r], 0.f));
          S[C1 + m * 40 + co] = (l1 >= 0 && l1 < 999) ? hv : (unsigned short)0;
        }
      }
    }
  }

  // stage wt2 slice 0 (256 chunks, 1/thread); prefetch before barrier
  {
    bf16x8 w2t = *(const bf16x8*)(wt2g + tid * 8);
    __syncthreads();  // conv1 done with wt1 bufs; s_c1 writes visible
    *(bf16x8*)&S[(tid >> 2) * 40 + (tid & 3) * 8] = w2t;
    __syncthreads();
  }

  // ---- conv2: kt-sliced wt2, (2 mt) x (4 nt) + wave0 mt=8
  {
    int mt0 = wave, mt1 = wave + 4;
    f32x4 acc[2][4], acc8[4];
#pragma unroll
    for (int nt = 0; nt < 4; ++nt) {
      float bv = cb2[nt * 16 + l15];
      acc[0][nt] = (f32x4){bv, bv, bv, bv};
      acc[1][nt] = (f32x4){bv, bv, bv, bv};
      acc8[nt] = (f32x4){bv, bv, bv, bv};
    }
    for (int kt = 0; kt < 6; ++kt) {
      bf16x8 w2t;
      if (kt < 5) w2t = *(const bf16x8*)(wt2g + (kt + 1) * 2048 + tid * 8);
      int wb = (kt & 1) * 2560;
      bf16x8 a0 = *(const bf16x8*)&S[C1 + (mt0 * 16 + l15 + kt) * 40 + quad * 8];
      bf16x8 a1 = *(const bf16x8*)&S[C1 + (mt1 * 16 + l15 + kt) * 40 + quad * 8];
#pragma unroll
      for (int nt = 0; nt < 4; ++nt) {
        bf16x8 bf = *(const bf16x8*)&S[wb + (nt * 16 + l15) * 40 + quad * 8];
        acc[0][nt] = __builtin_amdgcn_mfma_f32_16x16x32_bf16(a0, bf, acc[0][nt], 0, 0, 0);
        acc[1][nt] = __builtin_amdgcn_mfma_f32_16x16x32_bf16(a1, bf, acc[1][nt], 0, 0, 0);
      }
      if (wave == 0) {
        bf16x8 a8 = *(const bf16x8*)&S[C1 + (128 + l15 + kt) * 40 + quad * 8];
#pragma unroll
        for (int nt = 0; nt < 4; ++nt) {
          bf16x8 bf = *(const bf16x8*)&S[wb + (nt * 16 + l15) * 40 + quad * 8];
          acc8[nt] = __builtin_amdgcn_mfma_f32_16x16x32_bf16(a8, bf, acc8[nt], 0, 0, 0);
        }
      }
      if (kt < 5) {
        int wb2 = ((kt + 1) & 1) * 2560;
        *(bf16x8*)&S[wb2 + (tid >> 2) * 40 + (tid & 3) * 8] = w2t;
      }
      __syncthreads();
    }
#pragma unroll
    for (int mb = 0; mb < 2; ++mb) {
      int mt = mb ? mt1 : mt0;
#pragma unroll
      for (int nt = 0; nt < 4; ++nt) {
        int co = nt * 16 + l15;
#pragma unroll
        for (int r = 0; r < 4; ++r) {
          int m = mt * 16 + quad * 4 + r;
          int l2 = t0 - 3 + m;
          unsigned short hv = f2b(fmaxf(acc[mb][nt][r], 0.f));
          S[C2 + m * 72 + co] = (l2 >= 0 && l2 < 998) ? hv : (unsigned short)0;
        }
      }
    }
    if (wave == 0) {
#pragma unroll
      for (int nt = 0; nt < 4; ++nt) {
        int co = nt * 16 + l15;
#pragma unroll
        for (int r = 0; r < 4; ++r) {
          int m = 128 + quad * 4 + r;
          int l2 = t0 - 3 + m;
          unsigned short hv = f2b(fmaxf(acc8[nt][r], 0.f));
          S[C2 + m * 72 + co] = (l2 >= 0 && l2 < 998) ? hv : (unsigned short)0;
        }
      }
    }
  }

  // stage wt3 slice 0 (768 chunks, 3/thread); buf1 overlaps dead s_c1
  {
    bf16x8 w3t[3];
#pragma unroll
    for (int c = 0; c < 3; ++c) w3t[c] = *(const bf16x8*)(wt3g + (c * 256 + tid) * 8);
    __syncthreads();  // conv2 done with wt2 bufs + s_c1; s_c2 writes visible
#pragma unroll
    for (int c = 0; c < 3; ++c) {
      int ch = c * 256 + tid;
      int row = ch >> 3, col8 = ch & 7;
      *(bf16x8*)&S[row * 72 + col8 * 8] = w3t[c];
    }
    __syncthreads();
  }

  // ---- conv3: (2 mt) x (6 nt), wt3 kt-slices double-buffered @0/@6912
  {
    int mt0 = wave, mt1 = wave + 4;
    f32x4 acc[2][6];
#pragma unroll
    for (int nt = 0; nt < 6; ++nt) {
      float bv = cb3[nt * 16 + l15];
      acc[0][nt] = (f32x4){bv, bv, bv, bv};
      acc[1][nt] = (f32x4){bv, bv, bv, bv};
    }
    for (int kt = 0; kt < 8; ++kt) {
      bf16x8 w3t[3];
      if (kt < 7) {
#pragma unroll
        for (int c = 0; c < 3; ++c)
          w3t[c] = *(const bf16x8*)(wt3g + ((kt + 1) * 768 + c * 256 + tid) * 8);
      }
      int bo = (kt & 1) * 6912;
#pragma unroll
      for (int cb = 0; cb < 2; ++cb) {
        bf16x8 a0 = *(const bf16x8*)&S[C2 + (mt0 * 16 + l15 + kt) * 72 + cb * 32 + quad * 8];
        bf16x8 a1 = *(const bf16x8*)&S[C2 + (mt1 * 16 + l15 + kt) * 72 + cb * 32 + quad * 8];
#pragma unroll
        for (int nt = 0; nt < 6; ++nt) {
          bf16x8 bf = *(const bf16x8*)&S[bo + (nt * 16 + l15) * 72 + cb * 32 + quad * 8];
          acc[0][nt] = __builtin_amdgcn_mfma_f32_16x16x32_bf16(a0, bf, acc[0][nt], 0, 0, 0);
          acc[1][nt] = __builtin_amdgcn_mfma_f32_16x16x32_bf16(a1, bf, acc[1][nt], 0, 0, 0);
        }
      }
      if (kt < 7) {
        int bo2 = ((kt + 1) & 1) * 6912;
#pragma unroll
        for (int c = 0; c < 3; ++c) {
          int ch = c * 256 + tid;
          int row = ch >> 3, col8 = ch & 7;
          *(bf16x8*)&S[bo2 + row * 72 + col8 * 8] = w3t[c];
        }
      }
      __syncthreads();
    }
#pragma unroll
    for (int nt = 0; nt < 6; ++nt) {
      int co = nt * 16 + l15;
      float mx = 0.f;  // relu folded
#pragma unroll
      for (int mb = 0; mb < 2; ++mb) {
        int mt = mb ? mt1 : mt0;
#pragma unroll
        for (int r = 0; r < 4; ++r) {
          int l3 = t0 + mt * 16 + quad * 4 + r;
          if (l3 < 997) mx = fmaxf(mx, acc[mb][nt][r]);
        }
      }
      atomicMax(&Si[MAXI + co], __float_as_int(mx));
    }
  }
  __syncthreads();
  if (tid < 96) atomicMax((int*)&outmax[b * 224 + 128 + tid], Si[MAXI + tid]);
}

// ---------------- final 256 -> 1 ----------------
__global__ void k_fc3(const float* __restrict__ in, const float* __restrict__ w,
                      const float* __restrict__ bias, float* __restrict__ out) {
  int b = blockIdx.x * 256 + threadIdx.x;
  if (b >= NB) return;
  float acc = bias[0];
#pragma unroll 4
  for (int k = 0; k < 256; ++k) acc += in[b * 256 + k] * w[k];
  out[b] = acc;
}

extern "C" void kernel_launch(void* const* d_in, const int* in_sizes, int n_in,
                              void* d_out, int out_size, void* d_ws, size_t ws_size,
                              hipStream_t stream) {
  (void)in_sizes; (void)n_in; (void)out_size; (void)ws_size;
  const float* x = (const float*)d_in[0];
  const int* ei = (const int*)d_in[1];
  const int* batch = (const int*)d_in[2];
  const int* seq = (const int*)d_in[3];
  const float* W1 = (const float*)d_in[4];
  // b1/b2/b3 (d_in[5,9,13]) dropped: constant channel bias cancels in BatchNorm
  const float* g1 = (const float*)d_in[6];
  const float* bt1 = (const float*)d_in[7];
  const float* W2 = (const float*)d_in[8];
  const float* g2 = (const float*)d_in[10];
  const float* bt2 = (const float*)d_in[11];
  const float* W3 = (const float*)d_in[12];
  const float* g3 = (const float*)d_in[14];
  const float* bt3 = (const float*)d_in[15];
  const float* emb = (const float*)d_in[16];
  const float* ck1 = (const float*)d_in[17];
  const float* cb1 = (const float*)d_in[18];
  const float* ck2 = (const float*)d_in[19];
  const float* cb2 = (const float*)d_in[20];
  const float* ck3 = (const float*)d_in[21];
  const float* cb3 = (const float*)d_in[22];
  const float* fw1 = (const float*)d_in[23];
  const float* fb1 = (const float*)d_in[24];
  const float* fw2 = (const float*)d_in[25];
  const float* fb2 = (const float*)d_in[26];
  const float* fw3 = (const float*)d_in[27];
  const float* fb3 = (const float*)d_in[28];
  const int* src = ei;
  const int* dst = ei + NE;

  float* ws = (float*)d_ws;
  float* bufA = ws;                 // 32768*128 (16 MB)
  float* bufB = ws + 4194304;       // 32768*128 (16 MB)
  float* dis = ws + 8388608;        // 32768
  float* stats = ws + 8421376;      // 640 raw sums: L1 s@0 q@64 | L2 s@128 q@256 | L3 s@384 q@512
  float* cbuf = ws + 8422032;       // 512*224 (contiguous with stats: 1 memset)
  unsigned short* emb_bf = (unsigned short*)(ws + 8536832);  // 3328
  unsigned short* wt1 = emb_bf + 3328;                       // 16384
  unsigned short* wt2 = wt1 + 16384;                         // 12288
  unsigned short* wt3 = wt2 + 12288;                         // 49152
  int* degi = (int*)(ws + 8577408);       // 32768
  int* base = degi + NN;                  // 32769
  int* cursor = base + NN + 1;            // 32768
  unsigned short* csr_src = (unsigned short*)(cursor + NN);  // 131072 u16
  float* out = (float*)d_out;

  hipMemsetAsync(degi, 0, NN * sizeof(int), stream);
  hipMemsetAsync(stats, 0, (656 + NB * 224) * sizeof(float), stream);

  k_degprep<<<NE / 256, 256, 0, stream>>>(dst, degi, emb, ck1, ck2, ck3, emb_bf, wt1, wt2, wt3);
  k_scan<<<1, 1024, 0, stream>>>(degi, base, cursor, dis);
  k_fill<<<NE / 256, 256, 0, stream>>>(src, dst, cursor, csr_src, NE);

  // ---- GNN: 5 fused fat-grid kernels (pool fused into conv grid)
  k_gfc1s<<<NN / 256, 256, 0, stream>>>(x, dis, base, csr_src, W1, bufA, stats);
  k_gbngather<64><<<NN * 16 / 256, 256, 0, stream>>>(bufA, dis, base, csr_src, stats, g1, bt1, bufB);
  k_fc4<128, 64, 4, false, false, true><<<1024, 256, 0, stream>>>(bufB, W2, nullptr, bufA, stats + 128, NN);
  k_gbngather<128><<<NN * 32 / 256, 256, 0, stream>>>(bufA, dis, base, csr_src, stats + 128, g2, bt2, bufB);
  k_fc4<128, 128, 4, false, false, true><<<1024, 256, 0, stream>>>(bufB, W3, nullptr, bufA, stats + 384, NN);

  // ---- protein encoder + fused BN3/pool -> cbuf
  conv_mfma<<<dim3(9, NB), 256, 0, stream>>>(seq, emb_bf, wt1, cb1, wt2, cb2, wt3, cb3,
                                             bufA, stats + 384, g3, bt3, batch, cbuf);

  // ---- regressor
  k_fc4<512, 224, 4, true, true, false><<<64, 256, 0, stream>>>(cbuf, fw1, fb1, bufB, nullptr, NB);
  k_fc4<256, 512, 4, true, true, false><<<32, 256, 0, stream>>>(bufB, fw2, fb2, bufA, nullptr, NB);
  k_fc3<<<2, 256, 0, stream>>>(bufA, fw3, fb3, out);
}

// Round 17
// 461.463 us; speedup vs baseline: 1.1953x; 1.1953x over previous
//
#include <hip/hip_runtime.h>

#define NN 32768
#define NE 131072
#define NB 512
#define SL 1000

using bf16x8 = __attribute__((ext_vector_type(8))) short;
using f32x4  = __attribute__((ext_vector_type(4))) float;

static __device__ __forceinline__ unsigned short f2b(float f) {
  union { float f; unsigned u; } x; x.f = f;
  unsigned r = x.u + 0x7fffu + ((x.u >> 16) & 1u);  // RNE
  return (unsigned short)(r >> 16);
}

static __device__ __forceinline__ void bn_from_raw(float sum, float ssq, float g, float b,
                                                   float& sc, float& sh) {
  float m = sum / 32768.f;
  float v = ssq / 32768.f - m * m;
  sc = g * rsqrtf(v + 1e-5f);
  sh = b - m * sc;
}

// ---------------- fused degree + conv-weight prep ----------------
__global__ void k_degprep(const int* __restrict__ dst, int* __restrict__ degi,
                          const float* __restrict__ emb, const float* __restrict__ ck1,
                          const float* __restrict__ ck2, const float* __restrict__ ck3,
                          unsigned short* __restrict__ emb_bf, unsigned short* __restrict__ wt1,
                          unsigned short* __restrict__ wt2, unsigned short* __restrict__ wt3) {
  int gid = blockIdx.x * 256 + threadIdx.x;
  atomicAdd(&degi[dst[gid]], 1);
  int idx = gid;
  if (idx < 3328) {
    emb_bf[idx] = f2b(emb[idx]);
  } else if (idx < 3328 + 16384) {
    int i = idx - 3328;
    int kt = i >> 12, co = (i >> 7) & 31, ci = i & 127;
    wt1[i] = f2b(ck1[co * 512 + ci * 4 + kt]);
  } else if (idx < 3328 + 16384 + 12288) {
    int i = idx - 3328 - 16384;
    int kt = i >> 11, co = (i >> 5) & 63, ci = i & 31;
    wt2[i] = f2b(ck2[co * 192 + ci * 6 + kt]);
  } else if (idx < 3328 + 16384 + 12288 + 49152) {
    int i = idx - 3328 - 16384 - 12288;
    int kt = i / 6144, co = (i >> 6) % 96, ci = i & 63;
    wt3[i] = f2b(ck3[co * 512 + ci * 8 + kt]);
  }
}

__global__ void k_scan(const int* __restrict__ degi, int* __restrict__ base,
                       int* __restrict__ cursor, float* __restrict__ dis) {
  __shared__ int part[1024];
  int tid = threadIdx.x;
  int v[32];
  int s = 0;
  int lo = tid * 32;
#pragma unroll
  for (int i = 0; i < 32; ++i) { v[i] = degi[lo + i]; s += v[i]; }
  part[tid] = s;
  __syncthreads();
  for (int off = 1; off < 1024; off <<= 1) {
    int val = (tid >= off) ? part[tid - off] : 0;
    __syncthreads();
    part[tid] += val;
    __syncthreads();
  }
  int run = (tid > 0) ? part[tid - 1] : 0;
#pragma unroll
  for (int i = 0; i < 32; ++i) {
    base[lo + i] = run;
    cursor[lo + i] = run;
    dis[lo + i] = rsqrtf(1.0f + (float)v[i]);
    run += v[i];
  }
  if (tid == 1023) base[NN] = run;
}

__global__ void k_fill(const int* __restrict__ src, const int* __restrict__ dst,
                       int* __restrict__ cursor, unsigned short* __restrict__ csr_src, int E) {
  int e = blockIdx.x * 256 + threadIdx.x;
  if (e < E) {
    int d = dst[e];
    int pos = atomicAdd(&cursor[d], 1);
    csr_src[pos] = (unsigned short)src[e];
  }
}

// ---------------- L1: aggregate(x,5ch) + 5->64 fc + fused stats ----------------
__launch_bounds__(256)
__global__ void k_gfc1s(const float* __restrict__ x, const float* __restrict__ dis,
                        const int* __restrict__ base, const unsigned short* __restrict__ csr_src,
                        const float* __restrict__ W1, float* __restrict__ out,
                        float* __restrict__ st) {
  __shared__ float sW[5][64];
  __shared__ float a5[256][6];
  __shared__ float red[16][64];
  int tid = threadIdx.x;
  for (int i = tid; i < 320; i += 256) sW[i >> 6][i & 63] = W1[i];
  int n = blockIdx.x * 256 + tid;
  float dn = dis[n];
  float s2 = dn * dn;
  const float* xn = x + (long)n * 5;
  float a0 = xn[0] * s2, a1 = xn[1] * s2, a2 = xn[2] * s2, a3 = xn[3] * s2, a4 = xn[4] * s2;
  int b0 = base[n], b1 = base[n + 1];
  int sNext = (b0 < b1) ? csr_src[b0] : 0;
  for (int j = b0; j < b1; ++j) {
    int s = sNext;
    if (j + 1 < b1) sNext = csr_src[j + 1];
    float coef = dis[s] * dn;
    const float* xs = x + (long)s * 5;
    a0 += xs[0] * coef; a1 += xs[1] * coef; a2 += xs[2] * coef;
    a3 += xs[3] * coef; a4 += xs[4] * coef;
  }
  a5[tid][0] = a0; a5[tid][1] = a1; a5[tid][2] = a2; a5[tid][3] = a3; a5[tid][4] = a4;
  __syncthreads();
  int co = (tid & 15) * 4, strip = tid >> 4;
  float4 s4 = {0.f, 0.f, 0.f, 0.f}, ss4 = {0.f, 0.f, 0.f, 0.f};
  for (int i = 0; i < 16; ++i) {
    int nl = strip * 16 + i;
    long nn = (long)blockIdx.x * 256 + nl;
    float4 acc = {0.f, 0.f, 0.f, 0.f};
#pragma unroll
    for (int ci = 0; ci < 5; ++ci) {
      float av = a5[nl][ci];
      acc.x += av * sW[ci][co];     acc.y += av * sW[ci][co + 1];
      acc.z += av * sW[ci][co + 2]; acc.w += av * sW[ci][co + 3];
    }
    *(float4*)&out[nn * 64 + co] = acc;
    s4.x += acc.x; s4.y += acc.y; s4.z += acc.z; s4.w += acc.w;
    ss4.x += acc.x * acc.x; ss4.y += acc.y * acc.y;
    ss4.z += acc.z * acc.z; ss4.w += acc.w * acc.w;
  }
  *(float4*)&red[strip][co] = s4;
  __syncthreads();
  if (tid < 64) {
    float t = 0.f;
#pragma unroll
    for (int s = 0; s < 16; ++s) t += red[s][tid];
    atomicAdd(&st[tid], t);
  }
  __syncthreads();
  *(float4*)&red[strip][co] = ss4;
  __syncthreads();
  if (tid < 64) {
    float t = 0.f;
#pragma unroll
    for (int s = 0; s < 16; ++s) t += red[s][tid];
    atomicAdd(&st[64 + tid], t);
  }
}

// ---------------- gather with BN-on-load (raw-sum stats), index prefetch ----------------
template<int C>
__launch_bounds__(256)
__global__ void k_gbngather(const float* __restrict__ in, const float* __restrict__ dis,
                            const int* __restrict__ base, const unsigned short* __restrict__ csr_src,
                            const float* __restrict__ st, const float* __restrict__ g,
                            const float* __restrict__ bt, float* __restrict__ out) {
  constexpr int TPN = C / 4;
  int t = blockIdx.x * 256 + threadIdx.x;
  int n = t / TPN;
  int c = (t % TPN) * 4;
  float4 sum4 = *(const float4*)&st[c];
  float4 ssq4 = *(const float4*)&st[C + c];
  float4 gg = *(const float4*)&g[c];
  float4 bb = *(const float4*)&bt[c];
  float4 sc4, sh4;
  bn_from_raw(sum4.x, ssq4.x, gg.x, bb.x, sc4.x, sh4.x);
  bn_from_raw(sum4.y, ssq4.y, gg.y, bb.y, sc4.y, sh4.y);
  bn_from_raw(sum4.z, ssq4.z, gg.z, bb.z, sc4.z, sh4.z);
  bn_from_raw(sum4.w, ssq4.w, gg.w, bb.w, sc4.w, sh4.w);
  float dn = dis[n];
  float s2 = dn * dn;
  float4 a = *(const float4*)&in[(long)n * C + c];
  float4 acc;
  acc.x = fmaxf(a.x * sc4.x + sh4.x, 0.f) * s2;
  acc.y = fmaxf(a.y * sc4.y + sh4.y, 0.f) * s2;
  acc.z = fmaxf(a.z * sc4.z + sh4.z, 0.f) * s2;
  acc.w = fmaxf(a.w * sc4.w + sh4.w, 0.f) * s2;
  int b0 = base[n], b1 = base[n + 1];
  int sNext = (b0 < b1) ? csr_src[b0] : 0;
  for (int j = b0; j < b1; ++j) {
    int s = sNext;
    if (j + 1 < b1) sNext = csr_src[j + 1];
    float coef = dis[s] * dn;
    float4 vv = *(const float4*)&in[(long)s * C + c];
    acc.x += fmaxf(vv.x * sc4.x + sh4.x, 0.f) * coef;
    acc.y += fmaxf(vv.y * sc4.y + sh4.y, 0.f) * coef;
    acc.z += fmaxf(vv.z * sc4.z + sh4.z, 0.f) * coef;
    acc.w += fmaxf(vv.w * sc4.w + sh4.w, 0.f) * coef;
  }
  *(float4*)&out[(long)n * C + c] = acc;
}

// ---------------- register-tiled dense layer with fused stats (GNN fc layers) ----------------
template<int C_OUT, int K, int TN, bool RELU, bool BIAS, bool STATS>
__launch_bounds__(256)
__global__ void k_fc4(const float* __restrict__ in, const float* __restrict__ W,
                      const float* __restrict__ bias, float* __restrict__ out,
                      float* __restrict__ st, int N) {
  constexpr int CO4 = C_OUT / 4;
  constexpr int GPB = 256 / CO4;
  int g = blockIdx.x * GPB + threadIdx.x / CO4;
  long n0 = (long)g * TN;
  if (!STATS && n0 >= N) return;
  int co = (threadIdx.x % CO4) * 4;
  float4 acc[TN];
  float4 b4 = {0.f, 0.f, 0.f, 0.f};
  if (BIAS) b4 = *(const float4*)&bias[co];
#pragma unroll
  for (int t = 0; t < TN; ++t) acc[t] = b4;
  for (int ci = 0; ci < K; ci += 4) {
    float4 w0 = *(const float4*)&W[(long)(ci + 0) * C_OUT + co];
    float4 w1 = *(const float4*)&W[(long)(ci + 1) * C_OUT + co];
    float4 w2 = *(const float4*)&W[(long)(ci + 2) * C_OUT + co];
    float4 w3 = *(const float4*)&W[(long)(ci + 3) * C_OUT + co];
#pragma unroll
    for (int t = 0; t < TN; ++t) {
      float4 a = *(const float4*)&in[(n0 + t) * K + ci];
      acc[t].x += a.x * w0.x; acc[t].y += a.x * w0.y; acc[t].z += a.x * w0.z; acc[t].w += a.x * w0.w;
      acc[t].x += a.y * w1.x; acc[t].y += a.y * w1.y; acc[t].z += a.y * w1.z; acc[t].w += a.y * w1.w;
      acc[t].x += a.z * w2.x; acc[t].y += a.z * w2.y; acc[t].z += a.z * w2.z; acc[t].w += a.z * w2.w;
      acc[t].x += a.w * w3.x; acc[t].y += a.w * w3.y; acc[t].z += a.w * w3.z; acc[t].w += a.w * w3.w;
    }
  }
  float4 s4 = {0.f, 0.f, 0.f, 0.f}, ss4 = {0.f, 0.f, 0.f, 0.f};
#pragma unroll
  for (int t = 0; t < TN; ++t) {
    float4 o = acc[t];
    if (RELU) {
      o.x = fmaxf(o.x, 0.f); o.y = fmaxf(o.y, 0.f);
      o.z = fmaxf(o.z, 0.f); o.w = fmaxf(o.w, 0.f);
    }
    *(float4*)&out[(n0 + t) * C_OUT + co] = o;
    if (STATS) {
      s4.x += o.x; s4.y += o.y; s4.z += o.z; s4.w += o.w;
      ss4.x += o.x * o.x; ss4.y += o.y * o.y;
      ss4.z += o.z * o.z; ss4.w += o.w * o.w;
    }
  }
  if (STATS) {
    __shared__ float red2[GPB][C_OUT];
    int grp = threadIdx.x / CO4;
    *(float4*)&red2[grp][co] = s4;
    __syncthreads();
    if (threadIdx.x < C_OUT) {
      float t = 0.f;
#pragma unroll
      for (int s = 0; s < GPB; ++s) t += red2[s][threadIdx.x];
      atomicAdd(&st[threadIdx.x], t);
    }
    __syncthreads();
    *(float4*)&red2[grp][co] = ss4;
    __syncthreads();
    if (threadIdx.x < C_OUT) {
      float t = 0.f;
#pragma unroll
      for (int s = 0; s < GPB; ++s) t += red2[s][threadIdx.x];
      atomicAdd(&st[C_OUT + threadIdx.x], t);
    }
  }
}

// ---------------- fused regressor: per-sample 224 -> 512 -> 256 -> 1 ----------------
// One block per sample. Per-output ci-ascending accumulation matches k_fc4 bitwise
// for fc1/fc2; final dot uses a tree reduction (~1e-6 reorder noise).
__launch_bounds__(256)
__global__ void k_reg(const float* __restrict__ cbuf,
                      const float* __restrict__ fw1, const float* __restrict__ fb1,
                      const float* __restrict__ fw2, const float* __restrict__ fb2,
                      const float* __restrict__ fw3, const float* __restrict__ fb3,
                      float* __restrict__ out) {
  __shared__ float cin[224];
  __shared__ float h1[512];
  __shared__ float h2[256];
  __shared__ float red[4];
  int b = blockIdx.x, t = threadIdx.x;
  if (t < 224) cin[t] = cbuf[b * 224 + t];
  __syncthreads();
  // fc1: outputs t and t+256
  {
    float a0 = fb1[t], a1 = fb1[t + 256];
    for (int ci = 0; ci < 224; ++ci) {
      float av = cin[ci];
      a0 += av * fw1[ci * 512 + t];
      a1 += av * fw1[ci * 512 + t + 256];
    }
    h1[t] = fmaxf(a0, 0.f);
    h1[t + 256] = fmaxf(a1, 0.f);
  }
  __syncthreads();
  // fc2: output t
  {
    float a = fb2[t];
    for (int ci = 0; ci < 512; ++ci) a += h1[ci] * fw2[ci * 256 + t];
    h2[t] = fmaxf(a, 0.f);
  }
  __syncthreads();
  // fc3: dot(h2, fw3) + fb3
  {
    float p = h2[t] * fw3[t];
#pragma unroll
    for (int off = 32; off > 0; off >>= 1) p += __shfl_down(p, off, 64);
    if ((t & 63) == 0) red[t >> 6] = p;
    __syncthreads();
    if (t == 0) out[b] = red[0] + red[1] + red[2] + red[3] + fb3[0];
  }
}

// ---------------- protein encoder: bf16 MFMA (r15 version, verified 183us) + fused pool ----------------
// grid (9, NB): x<8 = conv tiles for batch y; x==8 = BN3+relu+mean-pool for batch y.
__launch_bounds__(256)
__global__ void conv_mfma(const int* __restrict__ seq, const unsigned short* __restrict__ emb_bf,
                          const unsigned short* __restrict__ wt1g, const float* __restrict__ cb1,
                          const unsigned short* __restrict__ wt2g, const float* __restrict__ cb2,
                          const unsigned short* __restrict__ wt3g, const float* __restrict__ cb3,
                          const float* __restrict__ agg, const float* __restrict__ st3,
                          const float* __restrict__ g3, const float* __restrict__ bt3,
                          const int* __restrict__ batch, float* __restrict__ outmax) {
  __shared__ __align__(16) unsigned short s_w[17408];
  __shared__ __align__(16) unsigned short s_c1[152][40];
  __shared__ __align__(16) unsigned short s_c2[144][72];
  __shared__ int s_tok[152];
  __shared__ int s_max[96];

  int tid = threadIdx.x;
  int b = blockIdx.y;

  if (blockIdx.x == 8) {  // ---- pooling block
    __shared__ int s_lo, s_hi;
    if (tid == 0) {
      int lo = 0, hi = NN;
      while (lo < hi) { int m = (lo + hi) >> 1; if (batch[m] < b) lo = m + 1; else hi = m; }
      s_lo = lo;
      hi = NN;
      while (lo < hi) { int m = (lo + hi) >> 1; if (batch[m] <= b) lo = m + 1; else hi = m; }
      s_hi = lo;
    }
    __syncthreads();
    if (tid < 128) {
      int lo = s_lo, hi = s_hi, c = tid;
      float sc, sh;
      bn_from_raw(st3[c], st3[128 + c], g3[c], bt3[c], sc, sh);
      float s = 0.f;
      for (int n = lo; n < hi; ++n) s += fmaxf(agg[(long)n * 128 + c] * sc + sh, 0.f);
      outmax[b * 224 + c] = s / fmaxf((float)(hi - lo), 1.0f);
    }
    return;
  }

  int t0 = blockIdx.x * 128;

  if (tid < 96) s_max[tid] = 0;
  if (tid < 152) {
    int p = t0 - 6 + tid;
    s_tok[tid] = (p >= 0 && p < SL) ? seq[b * SL + p] : 0;
  }
  if (tid < 160) ((int*)&s_c1[144][0])[tid] = 0;

  for (int c = 0; c < 8; ++c) {
    int ch = c * 256 + tid;
    int row = ch >> 4, col = (ch & 15) * 8;
    *(bf16x8*)&s_w[row * 136 + col] = *(const bf16x8*)(wt1g + ch * 8);
  }
  __syncthreads();

  int lane = tid & 63, wave = tid >> 6;
  int l15 = lane & 15, quad = lane >> 4;

  {
    int mt0 = wave, mt1 = wave + 4;
    f32x4 acc[2][2];
#pragma unroll
    for (int nt = 0; nt < 2; ++nt) {
      float bv = cb1[nt * 16 + l15];
      acc[0][nt] = (f32x4){bv, bv, bv, bv};
      acc[1][nt] = (f32x4){bv, bv, bv, bv};
    }
    for (int kt = 0; kt < 4; ++kt) {
      const unsigned short* e0 = emb_bf + s_tok[mt0 * 16 + l15 + kt] * 128 + quad * 8;
      const unsigned short* e1 = emb_bf + s_tok[mt1 * 16 + l15 + kt] * 128 + quad * 8;
#pragma unroll
      for (int cb = 0; cb < 4; ++cb) {
        bf16x8 a0 = *(const bf16x8*)(e0 + cb * 32);
        bf16x8 a1 = *(const bf16x8*)(e1 + cb * 32);
#pragma unroll
        for (int nt = 0; nt < 2; ++nt) {
          bf16x8 bf = *(const bf16x8*)&s_w[(kt * 32 + nt * 16 + l15) * 136 + cb * 32 + quad * 8];
          acc[0][nt] = __builtin_amdgcn_mfma_f32_16x16x32_bf16(a0, bf, acc[0][nt], 0, 0, 0);
          acc[1][nt] = __builtin_amdgcn_mfma_f32_16x16x32_bf16(a1, bf, acc[1][nt], 0, 0, 0);
        }
      }
    }
#pragma unroll
    for (int mb = 0; mb < 2; ++mb) {
      int mt = mb ? mt1 : mt0;
#pragma unroll
      for (int nt = 0; nt < 2; ++nt) {
        int co = nt * 16 + l15;
#pragma unroll
        for (int r = 0; r < 4; ++r) {
          int m = mt * 16 + quad * 4 + r;
          int l1 = t0 - 5 + m;
          unsigned short hv = f2b(fmaxf(acc[mb][nt][r], 0.f));
          s_c1[m][co] = (l1 >= 0 && l1 < 999) ? hv : (unsigned short)0;
        }
      }
    }
    if (wave == 0) {
      f32x4 acc8[2];
#pragma unroll
      for (int nt = 0; nt < 2; ++nt) {
        float bv = cb1[nt * 16 + l15];
        acc8[nt] = (f32x4){bv, bv, bv, bv};
      }
      for (int kt = 0; kt < 4; ++kt) {
        const unsigned short* e0 = emb_bf + s_tok[128 + l15 + kt] * 128 + quad * 8;
#pragma unroll
        for (int cb = 0; cb < 4; ++cb) {
          bf16x8 a0 = *(const bf16x8*)(e0 + cb * 32);
#pragma unroll
          for (int nt = 0; nt < 2; ++nt) {
            bf16x8 bf = *(const bf16x8*)&s_w[(kt * 32 + nt * 16 + l15) * 136 + cb * 32 + quad * 8];
            acc8[nt] = __builtin_amdgcn_mfma_f32_16x16x32_bf16(a0, bf, acc8[nt], 0, 0, 0);
          }
        }
      }
#pragma unroll
      for (int nt = 0; nt < 2; ++nt) {
        int co = nt * 16 + l15;
#pragma unroll
        for (int r = 0; r < 4; ++r) {
          int m = 128 + quad * 4 + r;
          int l1 = t0 - 5 + m;
          unsigned short hv = f2b(fmaxf(acc8[nt][r], 0.f));
          s_c1[m][co] = (l1 >= 0 && l1 < 999) ? hv : (unsigned short)0;
        }
      }
    }
  }

  {
    bf16x8 w2t[6];
#pragma unroll
    for (int c = 0; c < 6; ++c) w2t[c] = *(const bf16x8*)(wt2g + (c * 256 + tid) * 8);
    __syncthreads();
#pragma unroll
    for (int c = 0; c < 6; ++c) {
      int ch = c * 256 + tid;
      int row = ch >> 2, col = (ch & 3) * 8;
      *(bf16x8*)&s_w[row * 40 + col] = w2t[c];
    }
    __syncthreads();
  }

  {
    int mt0 = wave, mt1 = wave + 4;
    f32x4 acc[2][4];
#pragma unroll
    for (int nt = 0; nt < 4; ++nt) {
      float bv = cb2[nt * 16 + l15];
      acc[0][nt] = (f32x4){bv, bv, bv, bv};
      acc[1][nt] = (f32x4){bv, bv, bv, bv};
    }
    for (int kt = 0; kt < 6; ++kt) {
      bf16x8 a0 = *(const bf16x8*)&s_c1[mt0 * 16 + l15 + kt][quad * 8];
      bf16x8 a1 = *(const bf16x8*)&s_c1[mt1 * 16 + l15 + kt][quad * 8];
#pragma unroll
      for (int nt = 0; nt < 4; ++nt) {
        bf16x8 bf = *(const bf16x8*)&s_w[(kt * 64 + nt * 16 + l15) * 40 + quad * 8];
        acc[0][nt] = __builtin_amdgcn_mfma_f32_16x16x32_bf16(a0, bf, acc[0][nt], 0, 0, 0);
        acc[1][nt] = __builtin_amdgcn_mfma_f32_16x16x32_bf16(a1, bf, acc[1][nt], 0, 0, 0);
      }
    }
#pragma unroll
    for (int mb = 0; mb < 2; ++mb) {
      int mt = mb ? mt1 : mt0;
#pragma unroll
      for (int nt = 0; nt < 4; ++nt) {
        int co = nt * 16 + l15;
#pragma unroll
        for (int r = 0; r < 4; ++r) {
          int m = mt * 16 + quad * 4 + r;
          int l2 = t0 - 3 + m;
          unsigned short hv = f2b(fmaxf(acc[mb][nt][r], 0.f));
          s_c2[m][co] = (l2 >= 0 && l2 < 998) ? hv : (unsigned short)0;
        }
      }
    }
    if (wave == 0) {
      f32x4 acc8[4];
#pragma unroll
      for (int nt = 0; nt < 4; ++nt) {
        float bv = cb2[nt * 16 + l15];
        acc8[nt] = (f32x4){bv, bv, bv, bv};
      }
      for (int kt = 0; kt < 6; ++kt) {
        bf16x8 a0 = *(const bf16x8*)&s_c1[128 + l15 + kt][quad * 8];
#pragma unroll
        for (int nt = 0; nt < 4; ++nt) {
          bf16x8 bf = *(const bf16x8*)&s_w[(kt * 64 + nt * 16 + l15) * 40 + quad * 8];
          acc8[nt] = __builtin_amdgcn_mfma_f32_16x16x32_bf16(a0, bf, acc8[nt], 0, 0, 0);
        }
      }
#pragma unroll
      for (int nt = 0; nt < 4; ++nt) {
        int co = nt * 16 + l15;
#pragma unroll
        for (int r = 0; r < 4; ++r) {
          int m = 128 + quad * 4 + r;
          int l2 = t0 - 3 + m;
          unsigned short hv = f2b(fmaxf(acc8[nt][r], 0.f));
          s_c2[m][co] = (l2 >= 0 && l2 < 998) ? hv : (unsigned short)0;
        }
      }
    }
  }

  {
    bf16x8 w3t[3];
#pragma unroll
    for (int c = 0; c < 3; ++c) w3t[c] = *(const bf16x8*)(wt3g + (c * 256 + tid) * 8);
    __syncthreads();
#pragma unroll
    for (int c = 0; c < 3; ++c) {
      int ch = c * 256 + tid;
      int row = ch >> 3, col = (ch & 7) * 8;
      *(bf16x8*)&s_w[row * 72 + col] = w3t[c];
    }
    __syncthreads();
  }

  {
    int mt0 = wave, mt1 = wave + 4;
    f32x4 acc[2][6];
#pragma unroll
    for (int nt = 0; nt < 6; ++nt) {
      float bv = cb3[nt * 16 + l15];
      acc[0][nt] = (f32x4){bv, bv, bv, bv};
      acc[1][nt] = (f32x4){bv, bv, bv, bv};
    }
    for (int kt = 0; kt < 8; ++kt) {
      bf16x8 w3t[3];
      if (kt < 7) {
#pragma unroll
        for (int c = 0; c < 3; ++c)
          w3t[c] = *(const bf16x8*)(wt3g + ((kt + 1) * 768 + c * 256 + tid) * 8);
      }
      int bo = (kt & 1) * 6912;
#pragma unroll
      for (int cb = 0; cb < 2; ++cb) {
        bf16x8 a0 = *(const bf16x8*)&s_c2[mt0 * 16 + l15 + kt][cb * 32 + quad * 8];
        bf16x8 a1 = *(const bf16x8*)&s_c2[mt1 * 16 + l15 + kt][cb * 32 + quad * 8];
#pragma unroll
        for (int nt = 0; nt < 6; ++nt) {
          bf16x8 bf = *(const bf16x8*)&s_w[bo + (nt * 16 + l15) * 72 + cb * 32 + quad * 8];
          acc[0][nt] = __builtin_amdgcn_mfma_f32_16x16x32_bf16(a0, bf, acc[0][nt], 0, 0, 0);
          acc[1][nt] = __builtin_amdgcn_mfma_f32_16x16x32_bf16(a1, bf, acc[1][nt], 0, 0, 0);
        }
      }
      if (kt < 7) {
        int bo2 = ((kt + 1) & 1) * 6912;
#pragma unroll
        for (int c = 0; c < 3; ++c) {
          int ch = c * 256 + tid;
          int row = ch >> 3, col = (ch & 7) * 8;
          *(bf16x8*)&s_w[bo2 + row * 72 + col] = w3t[c];
        }
      }
      __syncthreads();
    }
#pragma unroll
    for (int nt = 0; nt < 6; ++nt) {
      int co = nt * 16 + l15;
      float mx = 0.f;
#pragma unroll
      for (int mb = 0; mb < 2; ++mb) {
        int mt = mb ? mt1 : mt0;
#pragma unroll
        for (int r = 0; r < 4; ++r) {
          int l3 = t0 + mt * 16 + quad * 4 + r;
          if (l3 < 997) mx = fmaxf(mx, acc[mb][nt][r]);
        }
      }
      atomicMax(&s_max[co], __float_as_int(mx));
    }
  }
  __syncthreads();
  if (tid < 96) atomicMax((int*)&outmax[b * 224 + 128 + tid], s_max[tid]);
}

extern "C" void kernel_launch(void* const* d_in, const int* in_sizes, int n_in,
                              void* d_out, int out_size, void* d_ws, size_t ws_size,
                              hipStream_t stream) {
  (void)in_sizes; (void)n_in; (void)out_size; (void)ws_size;
  const float* x = (const float*)d_in[0];
  const int* ei = (const int*)d_in[1];
  const int* batch = (const int*)d_in[2];
  const int* seq = (const int*)d_in[3];
  const float* W1 = (const float*)d_in[4];
  // b1/b2/b3 (d_in[5,9,13]) dropped: constant channel bias cancels in BatchNorm
  const float* g1 = (const float*)d_in[6];
  const float* bt1 = (const float*)d_in[7];
  const float* W2 = (const float*)d_in[8];
  const float* g2 = (const float*)d_in[10];
  const float* bt2 = (const float*)d_in[11];
  const float* W3 = (const float*)d_in[12];
  const float* g3 = (const float*)d_in[14];
  const float* bt3 = (const float*)d_in[15];
  const float* emb = (const float*)d_in[16];
  const float* ck1 = (const float*)d_in[17];
  const float* cb1 = (const float*)d_in[18];
  const float* ck2 = (const float*)d_in[19];
  const float* cb2 = (const float*)d_in[20];
  const float* ck3 = (const float*)d_in[21];
  const float* cb3 = (const float*)d_in[22];
  const float* fw1 = (const float*)d_in[23];
  const float* fb1 = (const float*)d_in[24];
  const float* fw2 = (const float*)d_in[25];
  const float* fb2 = (const float*)d_in[26];
  const float* fw3 = (const float*)d_in[27];
  const float* fb3 = (const float*)d_in[28];
  const int* src = ei;
  const int* dst = ei + NE;

  float* ws = (float*)d_ws;
  float* bufA = ws;                 // 32768*128 (16 MB)
  float* bufB = ws + 4194304;       // 32768*128 (16 MB)
  float* dis = ws + 8388608;        // 32768
  // contiguous zero region: stats(656) | cbuf(114688) | degi(32768 ints)
  float* stats = ws + 8421376;
  float* cbuf = ws + 8422032;
  int* degi = (int*)(ws + 8536720);
  int* base = degi + NN;                  // 32769
  int* cursor = base + NN + 1;
  unsigned short* csr_src = (unsigned short*)(cursor + NN);  // 131072 u16
  unsigned short* emb_bf = (unsigned short*)(ws + 8700564);  // 3328 (16B-aligned)
  unsigned short* wt1 = emb_bf + 3328;                       // 16384
  unsigned short* wt2 = wt1 + 16384;                         // 12288
  unsigned short* wt3 = wt2 + 12288;                         // 49152
  float* out = (float*)d_out;

  hipMemsetAsync(stats, 0, (656 + 114688 + 32768) * sizeof(float), stream);

  k_degprep<<<NE / 256, 256, 0, stream>>>(dst, degi, emb, ck1, ck2, ck3, emb_bf, wt1, wt2, wt3);
  k_scan<<<1, 1024, 0, stream>>>(degi, base, cursor, dis);
  k_fill<<<NE / 256, 256, 0, stream>>>(src, dst, cursor, csr_src, NE);

  // ---- GNN: 5 fused fat-grid kernels (pool fused into conv grid)
  k_gfc1s<<<NN / 256, 256, 0, stream>>>(x, dis, base, csr_src, W1, bufA, stats);
  k_gbngather<64><<<NN * 16 / 256, 256, 0, stream>>>(bufA, dis, base, csr_src, stats, g1, bt1, bufB);
  k_fc4<128, 64, 4, false, false, true><<<1024, 256, 0, stream>>>(bufB, W2, nullptr, bufA, stats + 128, NN);
  k_gbngather<128><<<NN * 32 / 256, 256, 0, stream>>>(bufA, dis, base, csr_src, stats + 128, g2, bt2, bufB);
  k_fc4<128, 128, 4, false, false, true><<<1024, 256, 0, stream>>>(bufB, W3, nullptr, bufA, stats + 384, NN);

  // ---- protein encoder + fused BN3/pool -> cbuf
  conv_mfma<<<dim3(9, NB), 256, 0, stream>>>(seq, emb_bf, wt1, cb1, wt2, cb2, wt3, cb3,
                                             bufA, stats + 384, g3, bt3, batch, cbuf);

  // ---- fused regressor (one block per sample)
  k_reg<<<NB, 256, 0, stream>>>(cbuf, fw1, fb1, fw2, fb2, fw3, fb3, out);
}